// Round 6
// baseline (542.993 us; speedup 1.0000x reference)
//
#include <hip/hip_runtime.h>
#include <hip/hip_bf16.h>

#define DD 128
#define NREL 8
#define LDHB 1032   // hb row stride (bf16): 2064B = 516 dwords = 4 mod 32 banks -> 2-way (free, m136)
#define BC 32       // cols per block
#define RECCAP 1024 // LDS record chunk (multiple of 8; padded block mean ~660, tail < 1024)

typedef float f32x4 __attribute__((ext_vector_type(4)));
typedef short short8 __attribute__((ext_vector_type(8)));

__device__ __forceinline__ float dis_f(float deg) {
    return deg == 0.0f ? 1.0f : rsqrtf(deg);
}

// In-degree per target col (50K addresses; ~13-way avg collisions, benign).
__global__ __launch_bounds__(256) void count_kernel(const int* __restrict__ ei,
                                                    int* __restrict__ cnt, int E) {
    int e = blockIdx.x * blockDim.x + threadIdx.x;
    if (e < E) atomicAdd(&cnt[ei[E + e]], 1);
}

// Exclusive scan of ROUNDUP8(cnt) -> pstart[N+1] (padded segment starts) + cursor copy.
__global__ __launch_bounds__(1024) void scan_kernel(const int* __restrict__ cnt,
                                                    int* __restrict__ pstart,
                                                    int* __restrict__ cursor, int N) {
    __shared__ int s[1024];
    const int t = threadIdx.x;
    const int chunk = (N + 1023) / 1024;
    const int beg = t * chunk, end = min(N, beg + chunk);
    int sum = 0;
    for (int c = beg; c < end; ++c) sum += (cnt[c] + 7) & ~7;
    s[t] = sum;
    __syncthreads();
    for (int off = 1; off < 1024; off <<= 1) {
        int add = (t >= off) ? s[t - off] : 0;
        __syncthreads();
        s[t] += add;
        __syncthreads();
    }
    int run = s[t] - sum;
    for (int c = beg; c < end; ++c) {
        pstart[c] = run; cursor[c] = run;
        run += (cnt[c] + 7) & ~7;
    }
    if (t == 1023) pstart[N] = s[1023];
}

// Place edge records sorted by col at padded bases: rec = (et<<16 | row, coef).
__global__ __launch_bounds__(256) void bucket_kernel(const int* __restrict__ ei,
                                                     const int* __restrict__ et,
                                                     const float* __restrict__ ew,
                                                     const int* __restrict__ cnt,
                                                     int* __restrict__ cursor,
                                                     uint2* __restrict__ ebuf, int E) {
    int e = blockIdx.x * blockDim.x + threadIdx.x;
    if (e >= E) return;
    const int row = ei[e], col = ei[E + e];
    const float coef = dis_f((float)cnt[row]) * dis_f((float)cnt[col]) * ew[e];
    const int pos = atomicAdd(&cursor[col], 1);
    ebuf[pos] = make_uint2(((unsigned)et[e] << 16) | (unsigned)row, __float_as_uint(coef));
}

// Fill per-col pad slots [pstart[c]+cnt[c], pstart[c+1]) with zero records (row 0, coef 0).
__global__ __launch_bounds__(256) void fill_kernel(const int* __restrict__ cnt,
                                                   const int* __restrict__ pstart,
                                                   uint2* __restrict__ ebuf, int N) {
    int idx = blockIdx.x * blockDim.x + threadIdx.x;
    const int c = idx >> 3, j = idx & 7;
    if (c >= N) return;
    const int pos = pstart[c] + cnt[c] + j;
    if (pos < pstart[c + 1]) ebuf[pos] = make_uint2(0u, 0u);
}

// BT[o][r*128+d] = bf16(W[r][d][o]) via LDS tile transpose (coalesced both sides).
__global__ __launch_bounds__(256) void wtrans_kernel(const float* __restrict__ W1,
                                                     const float* __restrict__ W2,
                                                     __hip_bfloat16* __restrict__ BT1,
                                                     __hip_bfloat16* __restrict__ BT2) {
    __shared__ __hip_bfloat16 tile[128][130];
    const int r = blockIdx.x & 7;
    const float* W = (blockIdx.x >> 3) ? W2 : W1;
    __hip_bfloat16* BT = (blockIdx.x >> 3) ? BT2 : BT1;
    const int o = threadIdx.x & 127;
    const int h = threadIdx.x >> 7;
    for (int d = h; d < DD; d += 2)
        tile[d][o] = __float2bfloat16(W[((size_t)r * DD + d) * DD + o]);
    __syncthreads();
    const int d = threadIdx.x & 127;
    for (int o2 = h; o2 < DD; o2 += 2)
        BT[(size_t)o2 * 1024 + r * DD + d] = tile[d][o2];
}

// x (fp32) -> xb (bf16), 4 elems/thread.
__global__ __launch_bounds__(256) void xcvt_kernel(const float* __restrict__ x,
                                                   __hip_bfloat16* __restrict__ xb, int total4) {
    int i = blockIdx.x * blockDim.x + threadIdx.x;
    if (i >= total4) return;
    const float4 a = ((const float4*)x)[i];
    __hip_bfloat162 p0 = __float22bfloat162_rn(make_float2(a.x, a.y));
    __hip_bfloat162 p1 = __float22bfloat162_rn(make_float2(a.z, a.w));
    uint2 u;
    u.x = *(unsigned int*)&p0;
    u.y = *(unsigned int*)&p1;
    *(uint2*)&xb[(size_t)i * 4] = u;
}

// Fused per-layer: records staged to LDS -> branchless scalar-addressed 8-deep register
// gather -> LDS h tile -> MFMA with BT. Block = 32 cols, 8 waves.
template<int LAYER>
__global__ __launch_bounds__(512, 4) void fused_kernel(const __hip_bfloat16* __restrict__ srcb,
                                                       const uint2* __restrict__ ebuf,
                                                       const int* __restrict__ pstart, // [N+1]
                                                       const __hip_bfloat16* __restrict__ BT,
                                                       const float* __restrict__ bias,
                                                       const float* __restrict__ x,
                                                       __hip_bfloat16* __restrict__ z1b,
                                                       float* __restrict__ out, int N) {
    __shared__ __hip_bfloat16 hb[BC][LDHB];
    __shared__ uint2 recs[RECCAP];
    const int tid = threadIdx.x;
    const int w = tid >> 6, l = tid & 63;
    const int c0 = blockIdx.x * BC;

    float acc[4][16];
    #pragma unroll
    for (int q = 0; q < 4; ++q)
        #pragma unroll
        for (int i = 0; i < 16; ++i) acc[q][i] = 0.f;

    const int B0 = pstart[c0];
    const int B1 = pstart[min(c0 + BC, N)];

    for (int cb = B0; cb < B1; cb += RECCAP) {
        const int ce = min(B1, cb + RECCAP);
        for (int i = cb + tid; i < ce; i += 512) recs[i - cb] = ebuf[i];
        __syncthreads();
        #pragma unroll
        for (int q = 0; q < 4; ++q) {
            const int c = c0 + w * 4 + q;
            if (c < N) {
                const int bc = __builtin_amdgcn_readfirstlane(pstart[c]);
                const int ec = __builtin_amdgcn_readfirstlane(pstart[c + 1]);
                const int lo = max(bc, cb), hi = min(ec, ce);
                // lo/hi are multiples of 8 (padded segments, RECCAP%8==0): full batches only.
                for (int e = lo; e < hi; e += 8) {
                    unsigned msv[8]; float cfv[8]; unsigned vv[8];
                    #pragma unroll
                    for (int i = 0; i < 8; ++i) {
                        const uint2 rr = recs[e - cb + i];
                        msv[i] = (unsigned)__builtin_amdgcn_readfirstlane((int)rr.x);
                        cfv[i] = __uint_as_float((unsigned)__builtin_amdgcn_readfirstlane((int)rr.y));
                    }
                    #pragma unroll
                    for (int i = 0; i < 8; ++i)
                        vv[i] = *(const unsigned*)&srcb[(size_t)(msv[i] & 0xffffu) * DD + 2 * l];
                    #pragma unroll
                    for (int i = 0; i < 8; ++i) {
                        const int etv = (int)(msv[i] >> 16);
                        const float xl = __uint_as_float(vv[i] << 16);
                        const float xh = __uint_as_float(vv[i] & 0xffff0000u);
                        #pragma unroll
                        for (int r = 0; r < NREL; ++r) {
                            const float cr = (etv == r) ? cfv[i] : 0.f;  // scalar cselect
                            acc[q][2 * r]     += cr * xl;
                            acc[q][2 * r + 1] += cr * xh;
                        }
                    }
                }
            }
        }
        __syncthreads();
    }

    // h -> LDS (bf16)
    #pragma unroll
    for (int q = 0; q < 4; ++q) {
        const int m = w * 4 + q;
        #pragma unroll
        for (int r = 0; r < NREL; ++r) {
            __hip_bfloat162 p = __float22bfloat162_rn(make_float2(acc[q][2 * r], acc[q][2 * r + 1]));
            *(unsigned int*)&hb[m][r * DD + 2 * l] = *(unsigned int*)&p;
        }
    }
    __syncthreads();

    // ---- MFMA: 2 row-tiles (rows 0-15, 16-31) x shared B-slice o=[w*16,w*16+16), K=1024
    const int lk = (l >> 4) * 8;
    const int lr = l & 15;
    f32x4 acc0 = {0.f, 0.f, 0.f, 0.f}, acc1 = {0.f, 0.f, 0.f, 0.f};
    const __hip_bfloat16* bt = BT + (size_t)(w * 16 + lr) * 1024 + lk;
    const __hip_bfloat16* h0 = &hb[lr][lk];
    const __hip_bfloat16* h1 = &hb[16 + lr][lk];
    #pragma unroll 8
    for (int k0 = 0; k0 < 1024; k0 += 32) {
        const short8 b  = *(const short8*)(bt + k0);
        const short8 a0 = *(const short8*)(h0 + k0);
        const short8 a1 = *(const short8*)(h1 + k0);
        acc0 = __builtin_amdgcn_mfma_f32_16x16x32_bf16(a0, b, acc0, 0, 0, 0);
        acc1 = __builtin_amdgcn_mfma_f32_16x16x32_bf16(a1, b, acc1, 0, 0, 0);
    }

    // ---- epilogue: D row=(l>>4)*4+q (graph col), col=l&15 (o)
    const int rbase = (l >> 4) * 4;
    const int o = w * 16 + lr;
    const float bv = bias[o];
    #pragma unroll
    for (int t = 0; t < 2; ++t) {
        const f32x4 av = t ? acc1 : acc0;
        #pragma unroll
        for (int q = 0; q < 4; ++q) {
            const int c = c0 + t * 16 + rbase + q;
            if (c >= N) continue;
            const size_t idx = (size_t)c * DD + o;
            float v = av[q] + bv;
            if (LAYER == 1) {
                v = v >= 0.f ? v : 0.01f * v;   // leaky_relu
                z1b[idx] = __float2bfloat16(v);
            } else {
                const float z1v = __bfloat162float(z1b[idx]);
                const float xv2 = x[idx];
                out[idx] = (xv2 + z1v + v) * 0.25f;                  // z_star
                out[(size_t)N * DD + idx] = (z1v + v) * (1.f / 3.f); // z_sharp
            }
        }
    }
}

extern "C" void kernel_launch(void* const* d_in, const int* in_sizes, int n_in,
                              void* d_out, int out_size, void* d_ws, size_t ws_size,
                              hipStream_t stream) {
    const float* x  = (const float*)d_in[0];
    const int*   ei = (const int*)d_in[1];
    const int*   et = (const int*)d_in[2];
    const float* ew = (const float*)d_in[3];
    const float* W1 = (const float*)d_in[4];
    const float* b1 = (const float*)d_in[5];
    const float* W2 = (const float*)d_in[6];
    const float* b2 = (const float*)d_in[7];

    const int N = in_sizes[0] / DD;
    const int E = in_sizes[3];
    float* out = (float*)d_out;

    // ws: cnt[N] | pstart[N+16] | cursor[N] | BT1 | BT2 | ebuf[E+8N] | xb | z1b  (~35 MiB)
    char* w = (char*)d_ws;
    int* cnt = (int*)w;                 w += (size_t)N * 4;
    int* pstart = (int*)w;              w += (size_t)(N + 16) * 4;
    int* cursor = (int*)w;              w += (size_t)N * 4;
    __hip_bfloat16* BT1 = (__hip_bfloat16*)w;  w += (size_t)DD * NREL * DD * 2;
    __hip_bfloat16* BT2 = (__hip_bfloat16*)w;  w += (size_t)DD * NREL * DD * 2;
    uint2* ebuf = (uint2*)w;            w += ((size_t)E + 8 * (size_t)N) * 8;
    __hip_bfloat16* xb = (__hip_bfloat16*)w;   w += (size_t)N * DD * 2;
    __hip_bfloat16* z1b = (__hip_bfloat16*)w;

    hipMemsetAsync(cnt, 0, (size_t)N * 4, stream);

    const int eb = (E + 255) / 256;
    count_kernel<<<eb, 256, 0, stream>>>(ei, cnt, E);
    wtrans_kernel<<<16, 256, 0, stream>>>(W1, W2, BT1, BT2);
    const int t4 = N * DD / 4;
    xcvt_kernel<<<(t4 + 255) / 256, 256, 0, stream>>>(x, xb, t4);
    scan_kernel<<<1, 1024, 0, stream>>>(cnt, pstart, cursor, N);
    bucket_kernel<<<eb, 256, 0, stream>>>(ei, et, ew, cnt, cursor, ebuf, E);
    fill_kernel<<<(N * 8 + 255) / 256, 256, 0, stream>>>(cnt, pstart, ebuf, N);

    const int nb = (N + BC - 1) / BC;
    fused_kernel<1><<<nb, 512, 0, stream>>>(xb,  ebuf, pstart, BT1, b1, x, z1b, out, N);
    fused_kernel<2><<<nb, 512, 0, stream>>>(z1b, ebuf, pstart, BT2, b2, x, z1b, out, N);
}